// Round 3
// baseline (2611.729 us; speedup 1.0000x reference)
//
#include <hip/hip_runtime.h>
#include <math.h>

#define DIN 128
#define NH 4
#define NC 32
#define HC 128
static constexpr float NEG_SLOPE = 0.2f;

__device__ __forceinline__ float leaky(float x) { return x > 0.f ? x : NEG_SLOPE * x; }

// ---------------------------------------------------------------------------
// K1: h = x @ W (128x128), a_src[n][H], a_dst[n][H].
// Register-blocked: 4 rows x 4 cols per thread. W in LDS as float4,
// x broadcast via __shfl within 32-lane column groups.
__global__ __launch_bounds__(256) void k_proj(
    const float* __restrict__ x, const float* __restrict__ W,
    const float* __restrict__ att_s, const float* __restrict__ att_d,
    float* __restrict__ h, float* __restrict__ a_src, float* __restrict__ a_dst, int n) {
  __shared__ float4 Wl[DIN * 32];  // [k][cgroup], 64 KiB
  int tid = threadIdx.x;
  for (int i = tid; i < DIN * 32; i += 256) Wl[i] = ((const float4*)W)[i];
  __syncthreads();

  int c = tid & 31;   // column group: cols 4c..4c+3 (head = c>>3)
  int g = tid >> 5;   // row group 0..7
  float4 as4 = ((const float4*)att_s)[c];
  float4 ad4 = ((const float4*)att_d)[c];

  // n == 100000 is a multiple of 32, so no row guards needed.
  for (int base = blockIdx.x * 32; base < n; base += gridDim.x * 32) {
    int row0 = base + g * 4;
    float xr[4][4];
#pragma unroll
    for (int r = 0; r < 4; ++r)
#pragma unroll
      for (int kk = 0; kk < 4; ++kk)
        xr[r][kk] = x[(size_t)(row0 + r) * DIN + kk * 32 + c];

    float4 acc[4];
#pragma unroll
    for (int r = 0; r < 4; ++r) acc[r] = make_float4(0.f, 0.f, 0.f, 0.f);

#pragma unroll
    for (int kk = 0; kk < 4; ++kk) {
#pragma unroll
      for (int k2 = 0; k2 < 32; ++k2) {
        float4 w4 = Wl[(kk * 32 + k2) * 32 + c];
#pragma unroll
        for (int r = 0; r < 4; ++r) {
          float xv = __shfl(xr[r][kk], k2, 32);
          acc[r].x = fmaf(xv, w4.x, acc[r].x);
          acc[r].y = fmaf(xv, w4.y, acc[r].y);
          acc[r].z = fmaf(xv, w4.z, acc[r].z);
          acc[r].w = fmaf(xv, w4.w, acc[r].w);
        }
      }
    }

#pragma unroll
    for (int r = 0; r < 4; ++r) {
      int row = row0 + r;
      ((float4*)h)[(size_t)row * 32 + c] = acc[r];
      float rs = acc[r].x * as4.x + acc[r].y * as4.y + acc[r].z * as4.z + acc[r].w * as4.w;
      float rd = acc[r].x * ad4.x + acc[r].y * ad4.y + acc[r].z * ad4.z + acc[r].w * ad4.w;
      // reduce across the 8 threads (consecutive lanes) sharing one head
#pragma unroll
      for (int m = 1; m <= 4; m <<= 1) {
        rs += __shfl_xor(rs, m, 64);
        rd += __shfl_xor(rd, m, 64);
      }
      if ((c & 7) == 0) {
        a_src[row * NH + (c >> 3)] = rs;
        a_dst[row * NH + (c >> 3)] = rd;
      }
    }
  }
}

// ---------------------------------------------------------------------------
__global__ void k_zero(int* __restrict__ cnt, float* __restrict__ wsumf, int n) {
  int i = blockIdx.x * blockDim.x + threadIdx.x;
  if (i < n) { cnt[i] = 0; wsumf[i] = 0.f; }
}

__global__ void k_count(const int* __restrict__ dst, const float* __restrict__ w,
                        int* __restrict__ cnt, float* __restrict__ wsumf, int E) {
  int e = blockIdx.x * blockDim.x + threadIdx.x;
  if (e < E) {
    int d = dst[e];
    atomicAdd(&cnt[d], 1);
    atomicAdd(&wsumf[d], w[e]);
  }
}

// scan1: block scans a 1024-chunk of cnt into off (exclusive), chunk total -> bsum
__global__ __launch_bounds__(256) void k_scan1(const int* __restrict__ cnt,
                                               int* __restrict__ off,
                                               int* __restrict__ bsum, int n) {
  __shared__ int lds[256];
  int b = blockIdx.x, t = threadIdx.x;
  int base = b * 1024 + t * 4;
  int v0 = 0, v1 = 0, v2 = 0, v3 = 0;
  if (base + 0 < n) v0 = cnt[base + 0];
  if (base + 1 < n) v1 = cnt[base + 1];
  if (base + 2 < n) v2 = cnt[base + 2];
  if (base + 3 < n) v3 = cnt[base + 3];
  int s = v0 + v1 + v2 + v3;
  lds[t] = s;
  __syncthreads();
  for (int ofs = 1; ofs < 256; ofs <<= 1) {
    int x = (t >= ofs) ? lds[t - ofs] : 0;
    __syncthreads();
    lds[t] += x;
    __syncthreads();
  }
  int run = (t > 0) ? lds[t - 1] : 0;
  if (t == 255) bsum[b] = lds[255];
  if (base + 0 < n) { off[base + 0] = run; run += v0; }
  if (base + 1 < n) { off[base + 1] = run; run += v1; }
  if (base + 2 < n) { off[base + 2] = run; run += v2; }
  if (base + 3 < n) { off[base + 3] = run; run += v3; }
}

__global__ __launch_bounds__(256) void k_scan2(int* __restrict__ bsum, int nb) {
  __shared__ int lds[256];
  int t = threadIdx.x;
  lds[t] = (t < nb) ? bsum[t] : 0;
  __syncthreads();
  for (int ofs = 1; ofs < 256; ofs <<= 1) {
    int x = (t >= ofs) ? lds[t - ofs] : 0;
    __syncthreads();
    lds[t] += x;
    __syncthreads();
  }
  int excl = (t > 0) ? lds[t - 1] : 0;
  if (t < nb) bsum[t] = excl;
}

__global__ void k_scan3(int* __restrict__ off, const int* __restrict__ bsum,
                        int* __restrict__ cursor, int n, int E) {
  int i = blockIdx.x * blockDim.x + threadIdx.x;
  if (i < n) {
    int v = off[i] + bsum[i >> 10];
    off[i] = v;
    cursor[i] = v;
  }
  if (i == 0) off[n] = E;
}

// ---------------------------------------------------------------------------
// scatter edges into dst-sorted order AND precompute per-(edge,head) exp.
__global__ void k_scatter(const int* __restrict__ ei, const float* __restrict__ w,
                          int* __restrict__ cursor,
                          int* __restrict__ esrc, float4* __restrict__ ex4,
                          const float* __restrict__ a_src, const float* __restrict__ a_dst,
                          int E) {
  int e = blockIdx.x * blockDim.x + threadIdx.x;
  if (e >= E) return;
  int s = ei[e], d = ei[E + e];
  float wv = w[e];
  int p = atomicAdd(&cursor[d], 1);
  esrc[p] = s;
  float lw = log2f(wv);
  const float4 as = *reinterpret_cast<const float4*>(a_src + s * NH);
  const float4 ad = *reinterpret_cast<const float4*>(a_dst + d * NH);
  float4 ev;
  ev.x = expf(leaky(as.x + ad.x) + lw);
  ev.y = expf(leaky(as.y + ad.y) + lw);
  ev.z = expf(leaky(as.z + ad.z) + lw);
  ev.w = expf(leaky(as.w + ad.w) + lw);
  ex4[p] = ev;
}

// ---------------------------------------------------------------------------
// gather-aggregate: 128 threads per node, minimal inner loop (loads + fma).
__global__ __launch_bounds__(256) void k_gather(
    const int* __restrict__ esrc, const float* __restrict__ ex,
    const int* __restrict__ off, const float* __restrict__ wsumf,
    const float* __restrict__ a_src, const float* __restrict__ a_dst,
    const float* __restrict__ h, const float* __restrict__ bias,
    float* __restrict__ out, int n) {
  int node = blockIdx.x * 2 + (threadIdx.x >> 7);
  if (node >= n) return;
  int j = threadIdx.x & 127;
  int hh = j >> 5;
  int beg = off[node], end = off[node + 1];
  float acc = 0.f, den = 0.f;
  int k = beg;
  for (; k + 2 <= end; k += 2) {
    int s0 = esrc[k], s1 = esrc[k + 1];
    float e0 = ex[k * 4 + hh], e1 = ex[(k + 1) * 4 + hh];
    float h0 = h[(size_t)s0 * HC + j], h1 = h[(size_t)s1 * HC + j];
    den += e0 + e1;
    acc = fmaf(e0, h0, fmaf(e1, h1, acc));
  }
  if (k < end) {
    int s0 = esrc[k];
    float e0 = ex[k * 4 + hh];
    den += e0;
    acc = fmaf(e0, h[(size_t)s0 * HC + j], acc);
  }
  int deg = end - beg;
  float lw = deg > 0 ? wsumf[node] / (float)deg : 1.f;
  float exs = expf(leaky(a_src[node * NH + hh] + a_dst[node * NH + hh]) + log2f(lw));
  den += exs;
  acc = fmaf(exs, h[(size_t)node * HC + j], acc);
  out[(size_t)node * HC + j] = acc / den + bias[j];
}

// ---------------------------------------------------------------------------
extern "C" void kernel_launch(void* const* d_in, const int* in_sizes, int n_in,
                              void* d_out, int out_size, void* d_ws, size_t ws_size,
                              hipStream_t stream) {
  const float* x       = (const float*)d_in[0];
  const int*   ei      = (const int*)d_in[1];   // [2][E]
  const float* eattr   = (const float*)d_in[2];
  const float* W       = (const float*)d_in[3];
  const float* att_src = (const float*)d_in[4];
  const float* att_dst = (const float*)d_in[5];
  const float* bias    = (const float*)d_in[6];
  float* out = (float*)d_out;

  const int n = in_sizes[0] / DIN;
  const int E = in_sizes[2];

  // workspace layout (all 16B-aligned: sizes are multiples of 16 bytes)
  float*  h     = (float*)d_ws;                     // n*HC
  float*  ex    = h + (size_t)n * HC;               // E*4
  int*    esrc  = (int*)(ex + (size_t)E * 4);       // E
  float*  a_src = (float*)(esrc + E);               // n*4
  float*  a_dst = a_src + (size_t)n * NH;           // n*4
  float*  wsumf = a_dst + (size_t)n * NH;           // n
  int*    off   = (int*)(wsumf + n);                // n+1
  int*    cnt   = off + n + 1;                      // n
  int*    cursor= cnt + n;                          // n
  int*    bsum  = cursor + n;                       // <=256

  const int* dst_idx = ei + E;
  int nb = (n + 1023) / 1024;

  k_proj<<<1024, 256, 0, stream>>>(x, W, att_src, att_dst, h, a_src, a_dst, n);
  k_zero<<<(n + 255) / 256, 256, 0, stream>>>(cnt, wsumf, n);
  k_count<<<(E + 255) / 256, 256, 0, stream>>>(dst_idx, eattr, cnt, wsumf, E);
  k_scan1<<<nb, 256, 0, stream>>>(cnt, off, bsum, n);
  k_scan2<<<1, 256, 0, stream>>>(bsum, nb);
  k_scan3<<<(n + 255) / 256, 256, 0, stream>>>(off, bsum, cursor, n, E);
  k_scatter<<<(E + 255) / 256, 256, 0, stream>>>(ei, eattr, cursor, esrc, (float4*)ex,
                                                 a_src, a_dst, E);
  k_gather<<<(n + 1) / 2, 256, 0, stream>>>(esrc, ex, off, wsumf, a_src, a_dst,
                                            h, bias, out, n);
}

// Round 4
// 630.080 us; speedup vs baseline: 4.1451x; 4.1451x over previous
//
#include <hip/hip_runtime.h>
#include <math.h>

#define DIN 128
#define NH 4
#define NC 32
#define HC 128
static constexpr float NEG_SLOPE = 0.2f;

__device__ __forceinline__ float leaky(float x) { return x > 0.f ? x : NEG_SLOPE * x; }

// ---------------------------------------------------------------------------
// K1: h = x @ W (128x128), a_src[n][H], a_dst[n][H]. W staged in LDS.
// One column per thread, 4 rows per thread (W LDS-read reused x4),
// x loaded as float4 (wave-broadcast, L1). No shuffles in the K loop,
// limited unroll -> low VGPR, no spills.
__global__ __launch_bounds__(256) void k_proj(
    const float* __restrict__ x, const float* __restrict__ W,
    const float* __restrict__ att_s, const float* __restrict__ att_d,
    float* __restrict__ h, float* __restrict__ a_src, float* __restrict__ a_dst, int n) {
  __shared__ float Wl[DIN * HC];  // 64 KiB
  int tid = threadIdx.x;
  for (int i = tid; i < DIN * HC; i += 256) Wl[i] = W[i];
  __syncthreads();

  int j = tid & 127;   // output column
  int sub = tid >> 7;  // 0/1: which 4-row group
  int hh = j >> 5;
  int lane32 = j & 31;
  float as = att_s[j], ad = att_d[j];

  // n == 100000 is a multiple of 8.
  for (int base = blockIdx.x * 8; base < n; base += gridDim.x * 8) {
    int row0 = base + sub * 4;
    if (row0 >= n) break;
    const float4* x0 = (const float4*)(x + (size_t)row0 * DIN);
    const float4* x1 = (const float4*)(x + (size_t)(row0 + 1) * DIN);
    const float4* x2 = (const float4*)(x + (size_t)(row0 + 2) * DIN);
    const float4* x3 = (const float4*)(x + (size_t)(row0 + 3) * DIN);
    float a0 = 0.f, a1 = 0.f, a2 = 0.f, a3 = 0.f;
#pragma unroll 4
    for (int k4 = 0; k4 < 32; ++k4) {
      float4 v0 = x0[k4], v1 = x1[k4], v2 = x2[k4], v3 = x3[k4];
      int kb = k4 * 4;
      float w0 = Wl[(kb + 0) * HC + j];
      float w1 = Wl[(kb + 1) * HC + j];
      float w2 = Wl[(kb + 2) * HC + j];
      float w3 = Wl[(kb + 3) * HC + j];
      a0 = fmaf(v0.x, w0, fmaf(v0.y, w1, fmaf(v0.z, w2, fmaf(v0.w, w3, a0))));
      a1 = fmaf(v1.x, w0, fmaf(v1.y, w1, fmaf(v1.z, w2, fmaf(v1.w, w3, a1))));
      a2 = fmaf(v2.x, w0, fmaf(v2.y, w1, fmaf(v2.z, w2, fmaf(v2.w, w3, a2))));
      a3 = fmaf(v3.x, w0, fmaf(v3.y, w1, fmaf(v3.z, w2, fmaf(v3.w, w3, a3))));
    }
    float accs[4] = {a0, a1, a2, a3};
#pragma unroll
    for (int r = 0; r < 4; ++r) {
      int row = row0 + r;
      h[(size_t)row * HC + j] = accs[r];
      float rs = accs[r] * as;
      float rd = accs[r] * ad;
#pragma unroll
      for (int m = 16; m >= 1; m >>= 1) {
        rs += __shfl_xor(rs, m, 64);
        rd += __shfl_xor(rd, m, 64);
      }
      if (lane32 == 0) {
        a_src[row * NH + hh] = rs;
        a_dst[row * NH + hh] = rd;
      }
    }
  }
}

// ---------------------------------------------------------------------------
__global__ void k_zero(int* __restrict__ cnt, float* __restrict__ wsumf, int n) {
  int i = blockIdx.x * blockDim.x + threadIdx.x;
  if (i < n) { cnt[i] = 0; wsumf[i] = 0.f; }
}

__global__ void k_count(const int* __restrict__ dst, const float* __restrict__ w,
                        int* __restrict__ cnt, float* __restrict__ wsumf, int E) {
  int e = blockIdx.x * blockDim.x + threadIdx.x;
  if (e < E) {
    int d = dst[e];
    atomicAdd(&cnt[d], 1);
    atomicAdd(&wsumf[d], w[e]);
  }
}

// scan1: block scans a 1024-chunk of cnt into off (exclusive), chunk total -> bsum
__global__ __launch_bounds__(256) void k_scan1(const int* __restrict__ cnt,
                                               int* __restrict__ off,
                                               int* __restrict__ bsum, int n) {
  __shared__ int lds[256];
  int b = blockIdx.x, t = threadIdx.x;
  int base = b * 1024 + t * 4;
  int v0 = 0, v1 = 0, v2 = 0, v3 = 0;
  if (base + 0 < n) v0 = cnt[base + 0];
  if (base + 1 < n) v1 = cnt[base + 1];
  if (base + 2 < n) v2 = cnt[base + 2];
  if (base + 3 < n) v3 = cnt[base + 3];
  int s = v0 + v1 + v2 + v3;
  lds[t] = s;
  __syncthreads();
  for (int ofs = 1; ofs < 256; ofs <<= 1) {
    int x = (t >= ofs) ? lds[t - ofs] : 0;
    __syncthreads();
    lds[t] += x;
    __syncthreads();
  }
  int run = (t > 0) ? lds[t - 1] : 0;
  if (t == 255) bsum[b] = lds[255];
  if (base + 0 < n) { off[base + 0] = run; run += v0; }
  if (base + 1 < n) { off[base + 1] = run; run += v1; }
  if (base + 2 < n) { off[base + 2] = run; run += v2; }
  if (base + 3 < n) { off[base + 3] = run; run += v3; }
}

__global__ __launch_bounds__(256) void k_scan2(int* __restrict__ bsum, int nb) {
  __shared__ int lds[256];
  int t = threadIdx.x;
  lds[t] = (t < nb) ? bsum[t] : 0;
  __syncthreads();
  for (int ofs = 1; ofs < 256; ofs <<= 1) {
    int x = (t >= ofs) ? lds[t - ofs] : 0;
    __syncthreads();
    lds[t] += x;
    __syncthreads();
  }
  int excl = (t > 0) ? lds[t - 1] : 0;
  if (t < nb) bsum[t] = excl;
}

__global__ void k_scan3(int* __restrict__ off, const int* __restrict__ bsum,
                        int* __restrict__ cursor, int n, int E) {
  int i = blockIdx.x * blockDim.x + threadIdx.x;
  if (i < n) {
    int v = off[i] + bsum[i >> 10];
    off[i] = v;
    cursor[i] = v;
  }
  if (i == 0) off[n] = E;
}

// ---------------------------------------------------------------------------
// scatter edges into dst-sorted order AND precompute per-(edge,head) exp.
__global__ void k_scatter(const int* __restrict__ ei, const float* __restrict__ w,
                          int* __restrict__ cursor,
                          int* __restrict__ esrc, float4* __restrict__ ex4,
                          const float* __restrict__ a_src, const float* __restrict__ a_dst,
                          int E) {
  int e = blockIdx.x * blockDim.x + threadIdx.x;
  if (e >= E) return;
  int s = ei[e], d = ei[E + e];
  float wv = w[e];
  int p = atomicAdd(&cursor[d], 1);
  esrc[p] = s;
  float lw = log2f(wv);
  const float4 as = *reinterpret_cast<const float4*>(a_src + s * NH);
  const float4 ad = *reinterpret_cast<const float4*>(a_dst + d * NH);
  float4 ev;
  ev.x = expf(leaky(as.x + ad.x) + lw);
  ev.y = expf(leaky(as.y + ad.y) + lw);
  ev.z = expf(leaky(as.z + ad.z) + lw);
  ev.w = expf(leaky(as.w + ad.w) + lw);
  ex4[p] = ev;
}

// ---------------------------------------------------------------------------
// gather-aggregate: 128 threads per node, minimal inner loop (loads + fma).
__global__ __launch_bounds__(256) void k_gather(
    const int* __restrict__ esrc, const float* __restrict__ ex,
    const int* __restrict__ off, const float* __restrict__ wsumf,
    const float* __restrict__ a_src, const float* __restrict__ a_dst,
    const float* __restrict__ h, const float* __restrict__ bias,
    float* __restrict__ out, int n) {
  int node = blockIdx.x * 2 + (threadIdx.x >> 7);
  if (node >= n) return;
  int j = threadIdx.x & 127;
  int hh = j >> 5;
  int beg = off[node], end = off[node + 1];
  float acc = 0.f, den = 0.f;
  int k = beg;
  for (; k + 2 <= end; k += 2) {
    int s0 = esrc[k], s1 = esrc[k + 1];
    float e0 = ex[k * 4 + hh], e1 = ex[(k + 1) * 4 + hh];
    float h0 = h[(size_t)s0 * HC + j], h1 = h[(size_t)s1 * HC + j];
    den += e0 + e1;
    acc = fmaf(e0, h0, fmaf(e1, h1, acc));
  }
  if (k < end) {
    int s0 = esrc[k];
    float e0 = ex[k * 4 + hh];
    den += e0;
    acc = fmaf(e0, h[(size_t)s0 * HC + j], acc);
  }
  int deg = end - beg;
  float lw = deg > 0 ? wsumf[node] / (float)deg : 1.f;
  float exs = expf(leaky(a_src[node * NH + hh] + a_dst[node * NH + hh]) + log2f(lw));
  den += exs;
  acc = fmaf(exs, h[(size_t)node * HC + j], acc);
  out[(size_t)node * HC + j] = acc / den + bias[j];
}

// ---------------------------------------------------------------------------
extern "C" void kernel_launch(void* const* d_in, const int* in_sizes, int n_in,
                              void* d_out, int out_size, void* d_ws, size_t ws_size,
                              hipStream_t stream) {
  const float* x       = (const float*)d_in[0];
  const int*   ei      = (const int*)d_in[1];   // [2][E]
  const float* eattr   = (const float*)d_in[2];
  const float* W       = (const float*)d_in[3];
  const float* att_src = (const float*)d_in[4];
  const float* att_dst = (const float*)d_in[5];
  const float* bias    = (const float*)d_in[6];
  float* out = (float*)d_out;

  const int n = in_sizes[0] / DIN;
  const int E = in_sizes[2];

  // workspace layout (all 16B-aligned)
  float*  h     = (float*)d_ws;                     // n*HC
  float*  ex    = h + (size_t)n * HC;               // E*4
  int*    esrc  = (int*)(ex + (size_t)E * 4);       // E
  float*  a_src = (float*)(esrc + E);               // n*4
  float*  a_dst = a_src + (size_t)n * NH;           // n*4
  float*  wsumf = a_dst + (size_t)n * NH;           // n
  int*    off   = (int*)(wsumf + n);                // n+1
  int*    cnt   = off + n + 1;                      // n
  int*    cursor= cnt + n;                          // n
  int*    bsum  = cursor + n;                       // <=256

  const int* dst_idx = ei + E;
  int nb = (n + 1023) / 1024;

  k_proj<<<2048, 256, 0, stream>>>(x, W, att_src, att_dst, h, a_src, a_dst, n);
  k_zero<<<(n + 255) / 256, 256, 0, stream>>>(cnt, wsumf, n);
  k_count<<<(E + 255) / 256, 256, 0, stream>>>(dst_idx, eattr, cnt, wsumf, E);
  k_scan1<<<nb, 256, 0, stream>>>(cnt, off, bsum, n);
  k_scan2<<<1, 256, 0, stream>>>(bsum, nb);
  k_scan3<<<(n + 255) / 256, 256, 0, stream>>>(off, bsum, cursor, n, E);
  k_scatter<<<(E + 255) / 256, 256, 0, stream>>>(ei, eattr, cursor, esrc, (float4*)ex,
                                                 a_src, a_dst, E);
  k_gather<<<(n + 1) / 2, 256, 0, stream>>>(esrc, ex, off, wsumf, a_src, a_dst,
                                            h, bias, out, n);
}

// Round 5
// 465.610 us; speedup vs baseline: 5.6093x; 1.3532x over previous
//
#include <hip/hip_runtime.h>
#include <math.h>

#define DIN 128
#define NH 4
#define NC 32
#define HC 128
static constexpr float NEG_SLOPE = 0.2f;

typedef __attribute__((ext_vector_type(8))) short bf16x8;
typedef __attribute__((ext_vector_type(4))) float f32x4;

__device__ __forceinline__ float leaky(float x) { return x > 0.f ? x : NEG_SLOPE * x; }

// RNE float->bf16 (finite inputs)
__device__ __forceinline__ short f2bf(float f) {
  unsigned u = __float_as_uint(f);
  unsigned r = (u + 0x7fffu + ((u >> 16) & 1u)) >> 16;
  return (short)r;
}

// ---------------------------------------------------------------------------
// K0: pre-swizzle W (fp32 [128][128] row-major k x col) into bf16 B-fragment
// layout for mfma_f32_16x16x32_bf16:
//   frag index g = (ntile*4 + ks)*64 + lane ; elem j=0..7
//   col = ntile*16 + (lane&15) ; k = ks*32 + (lane>>4)*8 + j
__global__ void k_wconv(const float* __restrict__ W, short* __restrict__ bswz) {
  int g = blockIdx.x * blockDim.x + threadIdx.x;   // 0..2047
  if (g >= 2048) return;
  int ntile = g >> 8;
  int ks = (g >> 6) & 3;
  int lane = g & 63;
  int col = (ntile << 4) + (lane & 15);
  int kb = ks * 32 + ((lane >> 4) << 3);
  short tmp[8];
#pragma unroll
  for (int j = 0; j < 8; ++j) tmp[j] = f2bf(W[(kb + j) * HC + col]);
  bf16x8 v;
#pragma unroll
  for (int j = 0; j < 8; ++j) v[j] = tmp[j];
  ((bf16x8*)bswz)[g] = v;
}

// ---------------------------------------------------------------------------
// K1: h = x @ W via MFMA. One wave per 16-row tile (n % 16 == 0 -> no tails).
// No LDS. A frags built from fp32 x with inline bf16 convert; B frags from
// the pre-swizzled 32KB table (L1/L2-resident). Also computes a_src/a_dst.
__global__ __launch_bounds__(256) void k_proj_mfma(
    const float* __restrict__ x, const short* __restrict__ bswz,
    const float* __restrict__ att_s, const float* __restrict__ att_d,
    float* __restrict__ h, float* __restrict__ a_src, float* __restrict__ a_dst, int n) {
  int wtile = blockIdx.x * 4 + (threadIdx.x >> 6);   // wave-tile index
  int ntiles = n >> 4;
  if (wtile >= ntiles) return;
  int lane = threadIdx.x & 63;
  int row0 = wtile << 4;

  // A fragments: lane holds row = row0+(lane&15), k = ks*32 + (lane>>4)*8 + j
  int arow = row0 + (lane & 15);
  int kbase = (lane >> 4) << 3;
  const float* xr = x + (size_t)arow * DIN;
  bf16x8 a[4];
#pragma unroll
  for (int ks = 0; ks < 4; ++ks) {
    float4 lo = *(const float4*)(xr + ks * 32 + kbase);
    float4 hi = *(const float4*)(xr + ks * 32 + kbase + 4);
    bf16x8 v;
    v[0] = f2bf(lo.x); v[1] = f2bf(lo.y); v[2] = f2bf(lo.z); v[3] = f2bf(lo.w);
    v[4] = f2bf(hi.x); v[5] = f2bf(hi.y); v[6] = f2bf(hi.z); v[7] = f2bf(hi.w);
    a[ks] = v;
  }

  const bf16x8* B = (const bf16x8*)bswz;
  int crow_base = row0 + ((lane >> 4) << 2);   // C/D: row=(lane>>4)*4+i
  int ccol_off = lane & 15;                    // C/D: col=lane&15

  float ra[4] = {0.f, 0.f, 0.f, 0.f};
  float rd[4] = {0.f, 0.f, 0.f, 0.f};

#pragma unroll
  for (int ntile = 0; ntile < 8; ++ntile) {
    f32x4 acc = {0.f, 0.f, 0.f, 0.f};
#pragma unroll
    for (int ks = 0; ks < 4; ++ks)
      acc = __builtin_amdgcn_mfma_f32_16x16x32_bf16(a[ks], B[(ntile * 4 + ks) * 64 + lane], acc, 0, 0, 0);
    int col = (ntile << 4) + ccol_off;
    float as = att_s[col], ad = att_d[col];
#pragma unroll
    for (int i = 0; i < 4; ++i) {
      h[(size_t)(crow_base + i) * HC + col] = acc[i];
      ra[i] = fmaf(acc[i], as, ra[i]);
      rd[i] = fmaf(acc[i], ad, rd[i]);
    }
    if (ntile & 1) {  // finished a head (cols [hh*32, hh*32+32))
      int hh = ntile >> 1;
#pragma unroll
      for (int i = 0; i < 4; ++i) {
#pragma unroll
        for (int m = 1; m <= 8; m <<= 1) {
          ra[i] += __shfl_xor(ra[i], m, 64);
          rd[i] += __shfl_xor(rd[i], m, 64);
        }
        if ((lane & 15) == 0) {
          a_src[(crow_base + i) * NH + hh] = ra[i];
          a_dst[(crow_base + i) * NH + hh] = rd[i];
        }
        ra[i] = 0.f; rd[i] = 0.f;
      }
    }
  }
}

// ---------------------------------------------------------------------------
__global__ void k_zero(int* __restrict__ cnt, float* __restrict__ wsumf, int n) {
  int i = blockIdx.x * blockDim.x + threadIdx.x;
  if (i < n) { cnt[i] = 0; wsumf[i] = 0.f; }
}

__global__ void k_count(const int* __restrict__ dst, const float* __restrict__ w,
                        int* __restrict__ cnt, float* __restrict__ wsumf, int E) {
  int e = blockIdx.x * blockDim.x + threadIdx.x;
  if (e < E) {
    int d = dst[e];
    atomicAdd(&cnt[d], 1);
    atomicAdd(&wsumf[d], w[e]);
  }
}

// scan1: block scans a 1024-chunk of cnt into off (exclusive), chunk total -> bsum
__global__ __launch_bounds__(256) void k_scan1(const int* __restrict__ cnt,
                                               int* __restrict__ off,
                                               int* __restrict__ bsum, int n) {
  __shared__ int lds[256];
  int b = blockIdx.x, t = threadIdx.x;
  int base = b * 1024 + t * 4;
  int v0 = 0, v1 = 0, v2 = 0, v3 = 0;
  if (base + 0 < n) v0 = cnt[base + 0];
  if (base + 1 < n) v1 = cnt[base + 1];
  if (base + 2 < n) v2 = cnt[base + 2];
  if (base + 3 < n) v3 = cnt[base + 3];
  int s = v0 + v1 + v2 + v3;
  lds[t] = s;
  __syncthreads();
  for (int ofs = 1; ofs < 256; ofs <<= 1) {
    int x = (t >= ofs) ? lds[t - ofs] : 0;
    __syncthreads();
    lds[t] += x;
    __syncthreads();
  }
  int run = (t > 0) ? lds[t - 1] : 0;
  if (t == 255) bsum[b] = lds[255];
  if (base + 0 < n) { off[base + 0] = run; run += v0; }
  if (base + 1 < n) { off[base + 1] = run; run += v1; }
  if (base + 2 < n) { off[base + 2] = run; run += v2; }
  if (base + 3 < n) { off[base + 3] = run; run += v3; }
}

__global__ __launch_bounds__(256) void k_scan2(int* __restrict__ bsum, int nb) {
  __shared__ int lds[256];
  int t = threadIdx.x;
  lds[t] = (t < nb) ? bsum[t] : 0;
  __syncthreads();
  for (int ofs = 1; ofs < 256; ofs <<= 1) {
    int x = (t >= ofs) ? lds[t - ofs] : 0;
    __syncthreads();
    lds[t] += x;
    __syncthreads();
  }
  int excl = (t > 0) ? lds[t - 1] : 0;
  if (t < nb) bsum[t] = excl;
}

__global__ void k_scan3(int* __restrict__ off, const int* __restrict__ bsum,
                        int* __restrict__ cursor, int n, int E) {
  int i = blockIdx.x * blockDim.x + threadIdx.x;
  if (i < n) {
    int v = off[i] + bsum[i >> 10];
    off[i] = v;
    cursor[i] = v;
  }
  if (i == 0) off[n] = E;
}

// ---------------------------------------------------------------------------
// scatter edges into dst-sorted order AND precompute per-(edge,head) exp.
__global__ void k_scatter(const int* __restrict__ ei, const float* __restrict__ w,
                          int* __restrict__ cursor,
                          int* __restrict__ esrc, float4* __restrict__ ex4,
                          const float* __restrict__ a_src, const float* __restrict__ a_dst,
                          int E) {
  int e = blockIdx.x * blockDim.x + threadIdx.x;
  if (e >= E) return;
  int s = ei[e], d = ei[E + e];
  float wv = w[e];
  int p = atomicAdd(&cursor[d], 1);
  esrc[p] = s;
  float lw = log2f(wv);
  const float4 as = *reinterpret_cast<const float4*>(a_src + s * NH);
  const float4 ad = *reinterpret_cast<const float4*>(a_dst + d * NH);
  float4 ev;
  ev.x = expf(leaky(as.x + ad.x) + lw);
  ev.y = expf(leaky(as.y + ad.y) + lw);
  ev.z = expf(leaky(as.z + ad.z) + lw);
  ev.w = expf(leaky(as.w + ad.w) + lw);
  ex4[p] = ev;
}

// ---------------------------------------------------------------------------
// gather-aggregate: 128 threads per node, minimal inner loop (loads + fma).
__global__ __launch_bounds__(256) void k_gather(
    const int* __restrict__ esrc, const float* __restrict__ ex,
    const int* __restrict__ off, const float* __restrict__ wsumf,
    const float* __restrict__ a_src, const float* __restrict__ a_dst,
    const float* __restrict__ h, const float* __restrict__ bias,
    float* __restrict__ out, int n) {
  int node = blockIdx.x * 2 + (threadIdx.x >> 7);
  if (node >= n) return;
  int j = threadIdx.x & 127;
  int hh = j >> 5;
  int beg = off[node], end = off[node + 1];
  float acc = 0.f, den = 0.f;
  int k = beg;
  for (; k + 2 <= end; k += 2) {
    int s0 = esrc[k], s1 = esrc[k + 1];
    float e0 = ex[k * 4 + hh], e1 = ex[(k + 1) * 4 + hh];
    float h0 = h[(size_t)s0 * HC + j], h1 = h[(size_t)s1 * HC + j];
    den += e0 + e1;
    acc = fmaf(e0, h0, fmaf(e1, h1, acc));
  }
  if (k < end) {
    int s0 = esrc[k];
    float e0 = ex[k * 4 + hh];
    den += e0;
    acc = fmaf(e0, h[(size_t)s0 * HC + j], acc);
  }
  int deg = end - beg;
  float lw = deg > 0 ? wsumf[node] / (float)deg : 1.f;
  float exs = expf(leaky(a_src[node * NH + hh] + a_dst[node * NH + hh]) + log2f(lw));
  den += exs;
  acc = fmaf(exs, h[(size_t)node * HC + j], acc);
  out[(size_t)node * HC + j] = acc / den + bias[j];
}

// ---------------------------------------------------------------------------
extern "C" void kernel_launch(void* const* d_in, const int* in_sizes, int n_in,
                              void* d_out, int out_size, void* d_ws, size_t ws_size,
                              hipStream_t stream) {
  const float* x       = (const float*)d_in[0];
  const int*   ei      = (const int*)d_in[1];   // [2][E]
  const float* eattr   = (const float*)d_in[2];
  const float* W       = (const float*)d_in[3];
  const float* att_src = (const float*)d_in[4];
  const float* att_dst = (const float*)d_in[5];
  const float* bias    = (const float*)d_in[6];
  float* out = (float*)d_out;

  const int n = in_sizes[0] / DIN;
  const int E = in_sizes[2];

  // workspace layout (16B-aligned at each float4-accessed array)
  float*  h     = (float*)d_ws;                     // n*HC
  float*  ex    = h + (size_t)n * HC;               // E*4
  int*    esrc  = (int*)(ex + (size_t)E * 4);       // E
  float*  a_src = (float*)(esrc + E);               // n*4
  float*  a_dst = a_src + (size_t)n * NH;           // n*4
  short*  bswz  = (short*)(a_dst + (size_t)n * NH); // 16384 bf16 (32 KB)
  float*  wsumf = (float*)(bswz + 16384);           // n
  int*    off   = (int*)(wsumf + n);                // n+1
  int*    cnt   = off + n + 1;                      // n
  int*    cursor= cnt + n;                          // n
  int*    bsum  = cursor + n;                       // <=256

  const int* dst_idx = ei + E;
  int nb = (n + 1023) / 1024;
  int wavetiles = n >> 4;                           // n % 16 == 0

  k_wconv<<<8, 256, 0, stream>>>(W, bswz);
  k_proj_mfma<<<(wavetiles + 3) / 4, 256, 0, stream>>>(x, bswz, att_src, att_dst,
                                                       h, a_src, a_dst, n);
  k_zero<<<(n + 255) / 256, 256, 0, stream>>>(cnt, wsumf, n);
  k_count<<<(E + 255) / 256, 256, 0, stream>>>(dst_idx, eattr, cnt, wsumf, E);
  k_scan1<<<nb, 256, 0, stream>>>(cnt, off, bsum, n);
  k_scan2<<<1, 256, 0, stream>>>(bsum, nb);
  k_scan3<<<(n + 255) / 256, 256, 0, stream>>>(off, bsum, cursor, n, E);
  k_scatter<<<(E + 255) / 256, 256, 0, stream>>>(ei, eattr, cursor, esrc, (float4*)ex,
                                                 a_src, a_dst, E);
  k_gather<<<(n + 1) / 2, 256, 0, stream>>>(esrc, ex, off, wsumf, a_src, a_dst,
                                            h, bias, out, n);
}

// Round 6
// 378.439 us; speedup vs baseline: 6.9013x; 1.2303x over previous
//
#include <hip/hip_runtime.h>
#include <math.h>

#define DIN 128
#define NH 4
#define NC 32
#define HC 128
static constexpr float NEG_SLOPE = 0.2f;

typedef __attribute__((ext_vector_type(8))) short bf16x8;
typedef __attribute__((ext_vector_type(4))) float f32x4;

__device__ __forceinline__ float leaky(float x) { return x > 0.f ? x : NEG_SLOPE * x; }

// RNE float->bf16 (finite inputs)
__device__ __forceinline__ unsigned short f2bf(float f) {
  unsigned u = __float_as_uint(f);
  unsigned r = (u + 0x7fffu + ((u >> 16) & 1u)) >> 16;
  return (unsigned short)r;
}
__device__ __forceinline__ float bf_lo(unsigned u) { return __uint_as_float(u << 16); }
__device__ __forceinline__ float bf_hi(unsigned u) { return __uint_as_float(u & 0xffff0000u); }

// ---------------------------------------------------------------------------
// K0: pre-swizzle W into the mfma_f32_16x16x32_bf16 B-fragment layout.
__global__ void k_wconv(const float* __restrict__ W, short* __restrict__ bswz) {
  int g = blockIdx.x * blockDim.x + threadIdx.x;   // 0..2047
  if (g >= 2048) return;
  int ntile = g >> 8;
  int ks = (g >> 6) & 3;
  int lane = g & 63;
  int col = (ntile << 4) + (lane & 15);
  int kb = ks * 32 + ((lane >> 4) << 3);
  bf16x8 v;
#pragma unroll
  for (int j = 0; j < 8; ++j) v[j] = (short)f2bf(W[(kb + j) * HC + col]);
  ((bf16x8*)bswz)[g] = v;
}

// ---------------------------------------------------------------------------
// K1: h = x @ W via MFMA, h stored as bf16. One wave per 16-row tile.
__global__ __launch_bounds__(256) void k_proj_mfma(
    const float* __restrict__ x, const short* __restrict__ bswz,
    const float* __restrict__ att_s, const float* __restrict__ att_d,
    unsigned short* __restrict__ hbf,
    float* __restrict__ a_src, float* __restrict__ a_dst, int n) {
  int wtile = blockIdx.x * 4 + (threadIdx.x >> 6);
  int ntiles = n >> 4;
  if (wtile >= ntiles) return;
  int lane = threadIdx.x & 63;
  int row0 = wtile << 4;

  int arow = row0 + (lane & 15);
  int kbase = (lane >> 4) << 3;
  const float* xr = x + (size_t)arow * DIN;
  bf16x8 a[4];
#pragma unroll
  for (int ks = 0; ks < 4; ++ks) {
    float4 lo = *(const float4*)(xr + ks * 32 + kbase);
    float4 hi = *(const float4*)(xr + ks * 32 + kbase + 4);
    bf16x8 v;
    v[0] = (short)f2bf(lo.x); v[1] = (short)f2bf(lo.y);
    v[2] = (short)f2bf(lo.z); v[3] = (short)f2bf(lo.w);
    v[4] = (short)f2bf(hi.x); v[5] = (short)f2bf(hi.y);
    v[6] = (short)f2bf(hi.z); v[7] = (short)f2bf(hi.w);
    a[ks] = v;
  }

  const bf16x8* B = (const bf16x8*)bswz;
  int crow_base = row0 + ((lane >> 4) << 2);
  int ccol_off = lane & 15;

  float ra[4] = {0.f, 0.f, 0.f, 0.f};
  float rd[4] = {0.f, 0.f, 0.f, 0.f};

#pragma unroll
  for (int ntile = 0; ntile < 8; ++ntile) {
    f32x4 acc = {0.f, 0.f, 0.f, 0.f};
#pragma unroll
    for (int ks = 0; ks < 4; ++ks)
      acc = __builtin_amdgcn_mfma_f32_16x16x32_bf16(a[ks], B[(ntile * 4 + ks) * 64 + lane], acc, 0, 0, 0);
    int col = (ntile << 4) + ccol_off;
    float as = att_s[col], ad = att_d[col];
#pragma unroll
    for (int i = 0; i < 4; ++i) {
      hbf[(size_t)(crow_base + i) * HC + col] = f2bf(acc[i]);
      ra[i] = fmaf(acc[i], as, ra[i]);
      rd[i] = fmaf(acc[i], ad, rd[i]);
    }
    if (ntile & 1) {
      int hh = ntile >> 1;
#pragma unroll
      for (int i = 0; i < 4; ++i) {
#pragma unroll
        for (int m = 1; m <= 8; m <<= 1) {
          ra[i] += __shfl_xor(ra[i], m, 64);
          rd[i] += __shfl_xor(rd[i], m, 64);
        }
        if ((lane & 15) == 0) {
          a_src[(crow_base + i) * NH + hh] = ra[i];
          a_dst[(crow_base + i) * NH + hh] = rd[i];
        }
        ra[i] = 0.f; rd[i] = 0.f;
      }
    }
  }
}

// ---------------------------------------------------------------------------
__global__ void k_zero(int* __restrict__ cnt, float* __restrict__ wsumf, int n) {
  int i = blockIdx.x * blockDim.x + threadIdx.x;
  if (i < n) { cnt[i] = 0; wsumf[i] = 0.f; }
}

__global__ void k_count(const int* __restrict__ dst, const float* __restrict__ w,
                        int* __restrict__ cnt, float* __restrict__ wsumf, int E) {
  int e = blockIdx.x * blockDim.x + threadIdx.x;
  if (e < E) {
    int d = dst[e];
    atomicAdd(&cnt[d], 1);
    atomicAdd(&wsumf[d], w[e]);
  }
}

__global__ __launch_bounds__(256) void k_scan1(const int* __restrict__ cnt,
                                               int* __restrict__ off,
                                               int* __restrict__ bsum, int n) {
  __shared__ int lds[256];
  int b = blockIdx.x, t = threadIdx.x;
  int base = b * 1024 + t * 4;
  int v0 = 0, v1 = 0, v2 = 0, v3 = 0;
  if (base + 0 < n) v0 = cnt[base + 0];
  if (base + 1 < n) v1 = cnt[base + 1];
  if (base + 2 < n) v2 = cnt[base + 2];
  if (base + 3 < n) v3 = cnt[base + 3];
  int s = v0 + v1 + v2 + v3;
  lds[t] = s;
  __syncthreads();
  for (int ofs = 1; ofs < 256; ofs <<= 1) {
    int x = (t >= ofs) ? lds[t - ofs] : 0;
    __syncthreads();
    lds[t] += x;
    __syncthreads();
  }
  int run = (t > 0) ? lds[t - 1] : 0;
  if (t == 255) bsum[b] = lds[255];
  if (base + 0 < n) { off[base + 0] = run; run += v0; }
  if (base + 1 < n) { off[base + 1] = run; run += v1; }
  if (base + 2 < n) { off[base + 2] = run; run += v2; }
  if (base + 3 < n) { off[base + 3] = run; run += v3; }
}

__global__ __launch_bounds__(256) void k_scan2(int* __restrict__ bsum, int nb) {
  __shared__ int lds[256];
  int t = threadIdx.x;
  lds[t] = (t < nb) ? bsum[t] : 0;
  __syncthreads();
  for (int ofs = 1; ofs < 256; ofs <<= 1) {
    int x = (t >= ofs) ? lds[t - ofs] : 0;
    __syncthreads();
    lds[t] += x;
    __syncthreads();
  }
  int excl = (t > 0) ? lds[t - 1] : 0;
  if (t < nb) bsum[t] = excl;
}

__global__ void k_scan3(int* __restrict__ off, const int* __restrict__ bsum,
                        int* __restrict__ cursor, int n, int E) {
  int i = blockIdx.x * blockDim.x + threadIdx.x;
  if (i < n) {
    int v = off[i] + bsum[i >> 10];
    off[i] = v;
    cursor[i] = v;
  }
  if (i == 0) off[n] = E;
}

// ---------------------------------------------------------------------------
// scatter edges into dst-sorted order AND precompute per-(edge,head) exp.
__global__ void k_scatter(const int* __restrict__ ei, const float* __restrict__ w,
                          int* __restrict__ cursor,
                          int* __restrict__ esrc, float4* __restrict__ ex4,
                          const float* __restrict__ a_src, const float* __restrict__ a_dst,
                          int E) {
  int e = blockIdx.x * blockDim.x + threadIdx.x;
  if (e >= E) return;
  int s = ei[e], d = ei[E + e];
  float wv = w[e];
  int p = atomicAdd(&cursor[d], 1);
  esrc[p] = s;
  float lw = log2f(wv);
  const float4 as = *reinterpret_cast<const float4*>(a_src + s * NH);
  const float4 ad = *reinterpret_cast<const float4*>(a_dst + d * NH);
  float4 ev;
  ev.x = expf(leaky(as.x + ad.x) + lw);
  ev.y = expf(leaky(as.y + ad.y) + lw);
  ev.z = expf(leaky(as.z + ad.z) + lw);
  ev.w = expf(leaky(as.w + ad.w) + lw);
  ex4[p] = ev;
}

// ---------------------------------------------------------------------------
// gather-aggregate: ONE wave per node; lane owns channels (2t, 2t+1) packed
// in one dword of bf16 h. 256 B/edge coalesced, 2 bit-ops + 2 FMA per dword.
__global__ __launch_bounds__(256) void k_gather(
    const int* __restrict__ esrc, const float* __restrict__ ex,
    const int* __restrict__ off, const float* __restrict__ wsumf,
    const float* __restrict__ a_src, const float* __restrict__ a_dst,
    const unsigned short* __restrict__ hbf, const float* __restrict__ bias,
    float* __restrict__ out, int n) {
  int node = blockIdx.x * 4 + (threadIdx.x >> 6);
  if (node >= n) return;
  int t = threadIdx.x & 63;
  int j2 = t * 2;          // channels j2, j2+1 (same head)
  int hh = t >> 4;
  int beg = off[node], end = off[node + 1];
  const float* exh = ex + hh;
  float acc0 = 0.f, acc1 = 0.f, den = 0.f;
  int k = beg;
  for (; k + 2 <= end; k += 2) {
    int s0 = esrc[k], s1 = esrc[k + 1];
    float e0 = exh[(size_t)k * 4], e1 = exh[(size_t)(k + 1) * 4];
    unsigned u0 = *(const unsigned*)(hbf + (size_t)s0 * HC + j2);
    unsigned u1 = *(const unsigned*)(hbf + (size_t)s1 * HC + j2);
    den += e0 + e1;
    acc0 = fmaf(e0, bf_lo(u0), fmaf(e1, bf_lo(u1), acc0));
    acc1 = fmaf(e0, bf_hi(u0), fmaf(e1, bf_hi(u1), acc1));
  }
  if (k < end) {
    int s0 = esrc[k];
    float e0 = exh[(size_t)k * 4];
    unsigned u0 = *(const unsigned*)(hbf + (size_t)s0 * HC + j2);
    den += e0;
    acc0 = fmaf(e0, bf_lo(u0), acc0);
    acc1 = fmaf(e0, bf_hi(u0), acc1);
  }
  int deg = end - beg;
  float lw = deg > 0 ? wsumf[node] / (float)deg : 1.f;
  float exs = expf(leaky(a_src[node * NH + hh] + a_dst[node * NH + hh]) + log2f(lw));
  den += exs;
  unsigned us = *(const unsigned*)(hbf + (size_t)node * HC + j2);
  acc0 = fmaf(exs, bf_lo(us), acc0);
  acc1 = fmaf(exs, bf_hi(us), acc1);
  float rden = 1.f / den;
  float2 o;
  o.x = acc0 * rden + bias[j2];
  o.y = acc1 * rden + bias[j2 + 1];
  *(float2*)(out + (size_t)node * HC + j2) = o;
}

// ---------------------------------------------------------------------------
extern "C" void kernel_launch(void* const* d_in, const int* in_sizes, int n_in,
                              void* d_out, int out_size, void* d_ws, size_t ws_size,
                              hipStream_t stream) {
  const float* x       = (const float*)d_in[0];
  const int*   ei      = (const int*)d_in[1];   // [2][E]
  const float* eattr   = (const float*)d_in[2];
  const float* W       = (const float*)d_in[3];
  const float* att_src = (const float*)d_in[4];
  const float* att_dst = (const float*)d_in[5];
  const float* bias    = (const float*)d_in[6];
  float* out = (float*)d_out;

  const int n = in_sizes[0] / DIN;
  const int E = in_sizes[2];

  // workspace layout (16B alignment maintained at each boundary)
  unsigned short* hbf = (unsigned short*)d_ws;        // n*HC bf16 (25.6 MB)
  float*  ex    = (float*)(hbf + (size_t)n * HC);     // E*4
  int*    esrc  = (int*)(ex + (size_t)E * 4);         // E
  float*  a_src = (float*)(esrc + E);                 // n*4
  float*  a_dst = a_src + (size_t)n * NH;             // n*4
  short*  bswz  = (short*)(a_dst + (size_t)n * NH);   // 16384 bf16 (32 KB)
  float*  wsumf = (float*)(bswz + 16384);             // n
  int*    off   = (int*)(wsumf + n);                  // n+1
  int*    cnt   = off + n + 1;                        // n
  int*    cursor= cnt + n;                            // n
  int*    bsum  = cursor + n;                         // <=256

  const int* dst_idx = ei + E;
  int nb = (n + 1023) / 1024;
  int wavetiles = n >> 4;

  k_wconv<<<8, 256, 0, stream>>>(W, bswz);
  k_proj_mfma<<<(wavetiles + 3) / 4, 256, 0, stream>>>(x, bswz, att_src, att_dst,
                                                       hbf, a_src, a_dst, n);
  k_zero<<<(n + 255) / 256, 256, 0, stream>>>(cnt, wsumf, n);
  k_count<<<(E + 255) / 256, 256, 0, stream>>>(dst_idx, eattr, cnt, wsumf, E);
  k_scan1<<<nb, 256, 0, stream>>>(cnt, off, bsum, n);
  k_scan2<<<1, 256, 0, stream>>>(bsum, nb);
  k_scan3<<<(n + 255) / 256, 256, 0, stream>>>(off, bsum, cursor, n, E);
  k_scatter<<<(E + 255) / 256, 256, 0, stream>>>(ei, eattr, cursor, esrc, (float4*)ex,
                                                 a_src, a_dst, E);
  k_gather<<<(n + 3) / 4, 256, 0, stream>>>(esrc, ex, off, wsumf, a_src, a_dst,
                                            hbf, bias, out, n);
}

// Round 7
// 291.185 us; speedup vs baseline: 8.9693x; 1.2997x over previous
//
#include <hip/hip_runtime.h>
#include <math.h>

#define DIN 128
#define NH 4
#define NC 32
#define HC 128
static constexpr float NEG_SLOPE = 0.2f;

typedef __attribute__((ext_vector_type(8))) short bf16x8;
typedef __attribute__((ext_vector_type(4))) float f32x4;

__device__ __forceinline__ float leaky(float x) { return x > 0.f ? x : NEG_SLOPE * x; }

// RNE float->bf16 (finite inputs)
__device__ __forceinline__ unsigned short f2bf(float f) {
  unsigned u = __float_as_uint(f);
  unsigned r = (u + 0x7fffu + ((u >> 16) & 1u)) >> 16;
  return (unsigned short)r;
}
__device__ __forceinline__ float bf_lo(unsigned u) { return __uint_as_float(u << 16); }
__device__ __forceinline__ float bf_hi(unsigned u) { return __uint_as_float(u & 0xffff0000u); }

static constexpr unsigned long long MASK40 = (1ull << 40) - 1;

// ---------------------------------------------------------------------------
// K0: pre-swizzle W into the mfma_f32_16x16x32_bf16 B-fragment layout.
__global__ void k_wconv(const float* __restrict__ W, short* __restrict__ bswz) {
  int g = blockIdx.x * blockDim.x + threadIdx.x;   // 0..2047
  if (g >= 2048) return;
  int ntile = g >> 8;
  int ks = (g >> 6) & 3;
  int lane = g & 63;
  int col = (ntile << 4) + (lane & 15);
  int kb = ks * 32 + ((lane >> 4) << 3);
  bf16x8 v;
#pragma unroll
  for (int j = 0; j < 8; ++j) v[j] = (short)f2bf(W[(kb + j) * HC + col]);
  ((bf16x8*)bswz)[g] = v;
}

// ---------------------------------------------------------------------------
// K1: h = x @ W via MFMA, h stored as bf16. One wave per 16-row tile.
__global__ __launch_bounds__(256) void k_proj_mfma(
    const float* __restrict__ x, const short* __restrict__ bswz,
    const float* __restrict__ att_s, const float* __restrict__ att_d,
    unsigned short* __restrict__ hbf,
    float* __restrict__ a_src, float* __restrict__ a_dst, int n) {
  int wtile = blockIdx.x * 4 + (threadIdx.x >> 6);
  int ntiles = n >> 4;
  if (wtile >= ntiles) return;
  int lane = threadIdx.x & 63;
  int row0 = wtile << 4;

  int arow = row0 + (lane & 15);
  int kbase = (lane >> 4) << 3;
  const float* xr = x + (size_t)arow * DIN;
  bf16x8 a[4];
#pragma unroll
  for (int ks = 0; ks < 4; ++ks) {
    float4 lo = *(const float4*)(xr + ks * 32 + kbase);
    float4 hi = *(const float4*)(xr + ks * 32 + kbase + 4);
    bf16x8 v;
    v[0] = (short)f2bf(lo.x); v[1] = (short)f2bf(lo.y);
    v[2] = (short)f2bf(lo.z); v[3] = (short)f2bf(lo.w);
    v[4] = (short)f2bf(hi.x); v[5] = (short)f2bf(hi.y);
    v[6] = (short)f2bf(hi.z); v[7] = (short)f2bf(hi.w);
    a[ks] = v;
  }

  const bf16x8* B = (const bf16x8*)bswz;
  int crow_base = row0 + ((lane >> 4) << 2);
  int ccol_off = lane & 15;

  float ra[4] = {0.f, 0.f, 0.f, 0.f};
  float rd[4] = {0.f, 0.f, 0.f, 0.f};

#pragma unroll
  for (int ntile = 0; ntile < 8; ++ntile) {
    f32x4 acc = {0.f, 0.f, 0.f, 0.f};
#pragma unroll
    for (int ks = 0; ks < 4; ++ks)
      acc = __builtin_amdgcn_mfma_f32_16x16x32_bf16(a[ks], B[(ntile * 4 + ks) * 64 + lane], acc, 0, 0, 0);
    int col = (ntile << 4) + ccol_off;
    float as = att_s[col], ad = att_d[col];
#pragma unroll
    for (int i = 0; i < 4; ++i) {
      hbf[(size_t)(crow_base + i) * HC + col] = f2bf(acc[i]);
      ra[i] = fmaf(acc[i], as, ra[i]);
      rd[i] = fmaf(acc[i], ad, rd[i]);
    }
    if (ntile & 1) {
      int hh = ntile >> 1;
#pragma unroll
      for (int i = 0; i < 4; ++i) {
#pragma unroll
        for (int m = 1; m <= 8; m <<= 1) {
          ra[i] += __shfl_xor(ra[i], m, 64);
          rd[i] += __shfl_xor(rd[i], m, 64);
        }
        if ((lane & 15) == 0) {
          a_src[(crow_base + i) * NH + hh] = ra[i];
          a_dst[(crow_base + i) * NH + hh] = rd[i];
        }
        ra[i] = 0.f; rd[i] = 0.f;
      }
    }
  }
}

// ---------------------------------------------------------------------------
__global__ void k_zero(unsigned long long* __restrict__ cw, int n) {
  int i = blockIdx.x * blockDim.x + threadIdx.x;
  if (i < n) cw[i] = 0ull;
}

// K2: ONE packed 64-bit atomic per edge: count in bits [40,64),
// fixed-point (2^32 scale) weight-sum in bits [0,40). Returned old value
// gives this edge's within-node rank -> no atomic needed in scatter.
__global__ void k_count(const int* __restrict__ dst, const float* __restrict__ w,
                        unsigned long long* __restrict__ cw,
                        unsigned short* __restrict__ rank, int E) {
  int e = blockIdx.x * blockDim.x + threadIdx.x;
  if (e < E) {
    int d = dst[e];
    unsigned long long fx = (unsigned long long)((double)w[e] * 4294967296.0);
    unsigned long long old = atomicAdd(&cw[d], (1ull << 40) | fx);
    rank[e] = (unsigned short)(old >> 40);
  }
}

// scan1: block scans a 1024-chunk of counts into off (exclusive), chunk total -> bsum
__global__ __launch_bounds__(256) void k_scan1(const unsigned long long* __restrict__ cw,
                                               int* __restrict__ off,
                                               int* __restrict__ bsum, int n) {
  __shared__ int lds[256];
  int b = blockIdx.x, t = threadIdx.x;
  int base = b * 1024 + t * 4;
  int v0 = 0, v1 = 0, v2 = 0, v3 = 0;
  if (base + 0 < n) v0 = (int)(cw[base + 0] >> 40);
  if (base + 1 < n) v1 = (int)(cw[base + 1] >> 40);
  if (base + 2 < n) v2 = (int)(cw[base + 2] >> 40);
  if (base + 3 < n) v3 = (int)(cw[base + 3] >> 40);
  int s = v0 + v1 + v2 + v3;
  lds[t] = s;
  __syncthreads();
  for (int ofs = 1; ofs < 256; ofs <<= 1) {
    int x = (t >= ofs) ? lds[t - ofs] : 0;
    __syncthreads();
    lds[t] += x;
    __syncthreads();
  }
  int run = (t > 0) ? lds[t - 1] : 0;
  if (t == 255) bsum[b] = lds[255];
  if (base + 0 < n) { off[base + 0] = run; run += v0; }
  if (base + 1 < n) { off[base + 1] = run; run += v1; }
  if (base + 2 < n) { off[base + 2] = run; run += v2; }
  if (base + 3 < n) { off[base + 3] = run; run += v3; }
}

__global__ __launch_bounds__(256) void k_scan2(int* __restrict__ bsum, int nb) {
  __shared__ int lds[256];
  int t = threadIdx.x;
  lds[t] = (t < nb) ? bsum[t] : 0;
  __syncthreads();
  for (int ofs = 1; ofs < 256; ofs <<= 1) {
    int x = (t >= ofs) ? lds[t - ofs] : 0;
    __syncthreads();
    lds[t] += x;
    __syncthreads();
  }
  int excl = (t > 0) ? lds[t - 1] : 0;
  if (t < nb) bsum[t] = excl;
}

__global__ void k_scan3(int* __restrict__ off, const int* __restrict__ bsum, int n, int E) {
  int i = blockIdx.x * blockDim.x + threadIdx.x;
  if (i < n) off[i] = off[i] + bsum[i >> 10];
  if (i == 0) off[n] = E;
}

// ---------------------------------------------------------------------------
// scatter edges into dst-sorted slots (off[d]+rank[e], NO atomics) and
// precompute per-(edge,head) exp.
__global__ void k_scatter(const int* __restrict__ ei, const float* __restrict__ w,
                          const int* __restrict__ off, const unsigned short* __restrict__ rank,
                          int* __restrict__ esrc, float4* __restrict__ ex4,
                          const float* __restrict__ a_src, const float* __restrict__ a_dst,
                          int E) {
  int e = blockIdx.x * blockDim.x + threadIdx.x;
  if (e >= E) return;
  int s = ei[e], d = ei[E + e];
  float wv = w[e];
  int p = off[d] + (int)rank[e];
  esrc[p] = s;
  float lw = log2f(wv);
  const float4 as = *reinterpret_cast<const float4*>(a_src + s * NH);
  const float4 ad = *reinterpret_cast<const float4*>(a_dst + d * NH);
  float4 ev;
  ev.x = expf(leaky(as.x + ad.x) + lw);
  ev.y = expf(leaky(as.y + ad.y) + lw);
  ev.z = expf(leaky(as.z + ad.z) + lw);
  ev.w = expf(leaky(as.w + ad.w) + lw);
  ex4[p] = ev;
}

// ---------------------------------------------------------------------------
// gather-aggregate: ONE wave per node; lane owns channels (2t, 2t+1) packed
// in one dword of bf16 h.
__global__ __launch_bounds__(256) void k_gather(
    const int* __restrict__ esrc, const float* __restrict__ ex,
    const int* __restrict__ off, const unsigned long long* __restrict__ cw,
    const float* __restrict__ a_src, const float* __restrict__ a_dst,
    const unsigned short* __restrict__ hbf, const float* __restrict__ bias,
    float* __restrict__ out, int n) {
  int node = blockIdx.x * 4 + (threadIdx.x >> 6);
  if (node >= n) return;
  int t = threadIdx.x & 63;
  int j2 = t * 2;          // channels j2, j2+1 (same head)
  int hh = t >> 4;
  int beg = off[node], end = off[node + 1];
  const float* exh = ex + hh;
  float acc0 = 0.f, acc1 = 0.f, den = 0.f;
  int k = beg;
  for (; k + 2 <= end; k += 2) {
    int s0 = esrc[k], s1 = esrc[k + 1];
    float e0 = exh[(size_t)k * 4], e1 = exh[(size_t)(k + 1) * 4];
    unsigned u0 = *(const unsigned*)(hbf + (size_t)s0 * HC + j2);
    unsigned u1 = *(const unsigned*)(hbf + (size_t)s1 * HC + j2);
    den += e0 + e1;
    acc0 = fmaf(e0, bf_lo(u0), fmaf(e1, bf_lo(u1), acc0));
    acc1 = fmaf(e0, bf_hi(u0), fmaf(e1, bf_hi(u1), acc1));
  }
  if (k < end) {
    int s0 = esrc[k];
    float e0 = exh[(size_t)k * 4];
    unsigned u0 = *(const unsigned*)(hbf + (size_t)s0 * HC + j2);
    den += e0;
    acc0 = fmaf(e0, bf_lo(u0), acc0);
    acc1 = fmaf(e0, bf_hi(u0), acc1);
  }
  int deg = end - beg;
  float lw = 1.f;
  if (deg > 0) {
    double ws = (double)(cw[node] & MASK40) * (1.0 / 4294967296.0);
    lw = (float)(ws / (double)deg);
  }
  float exs = expf(leaky(a_src[node * NH + hh] + a_dst[node * NH + hh]) + log2f(lw));
  den += exs;
  unsigned us = *(const unsigned*)(hbf + (size_t)node * HC + j2);
  acc0 = fmaf(exs, bf_lo(us), acc0);
  acc1 = fmaf(exs, bf_hi(us), acc1);
  float rden = 1.f / den;
  float2 o;
  o.x = acc0 * rden + bias[j2];
  o.y = acc1 * rden + bias[j2 + 1];
  *(float2*)(out + (size_t)node * HC + j2) = o;
}

// ---------------------------------------------------------------------------
extern "C" void kernel_launch(void* const* d_in, const int* in_sizes, int n_in,
                              void* d_out, int out_size, void* d_ws, size_t ws_size,
                              hipStream_t stream) {
  const float* x       = (const float*)d_in[0];
  const int*   ei      = (const int*)d_in[1];   // [2][E]
  const float* eattr   = (const float*)d_in[2];
  const float* W       = (const float*)d_in[3];
  const float* att_src = (const float*)d_in[4];
  const float* att_dst = (const float*)d_in[5];
  const float* bias    = (const float*)d_in[6];
  float* out = (float*)d_out;

  const int n = in_sizes[0] / DIN;
  const int E = in_sizes[2];

  // workspace layout (n even, E even -> all boundaries stay 8/16B aligned)
  unsigned short* hbf = (unsigned short*)d_ws;            // n*HC bf16 (25.6 MB)
  float*  ex    = (float*)(hbf + (size_t)n * HC);         // E*4 f32
  int*    esrc  = (int*)(ex + (size_t)E * 4);             // E
  float*  a_src = (float*)(esrc + E);                     // n*4
  float*  a_dst = a_src + (size_t)n * NH;                 // n*4
  short*  bswz  = (short*)(a_dst + (size_t)n * NH);       // 16384 bf16 (32 KB)
  unsigned long long* cw = (unsigned long long*)(bswz + 16384);  // n u64
  int*    off   = (int*)(cw + n);                         // n+1
  unsigned short* rank = (unsigned short*)(off + n + 1);  // E u16
  int*    bsum  = (int*)(rank + E);                       // <=256

  const int* dst_idx = ei + E;
  int nb = (n + 1023) / 1024;
  int wavetiles = n >> 4;

  k_wconv<<<8, 256, 0, stream>>>(W, bswz);
  k_proj_mfma<<<(wavetiles + 3) / 4, 256, 0, stream>>>(x, bswz, att_src, att_dst,
                                                       hbf, a_src, a_dst, n);
  k_zero<<<(n + 255) / 256, 256, 0, stream>>>(cw, n);
  k_count<<<(E + 255) / 256, 256, 0, stream>>>(dst_idx, eattr, cw, rank, E);
  k_scan1<<<nb, 256, 0, stream>>>(cw, off, bsum, n);
  k_scan2<<<1, 256, 0, stream>>>(bsum, nb);
  k_scan3<<<(n + 255) / 256, 256, 0, stream>>>(off, bsum, n, E);
  k_scatter<<<(E + 255) / 256, 256, 0, stream>>>(ei, eattr, off, rank, esrc, (float4*)ex,
                                                 a_src, a_dst, E);
  k_gather<<<(n + 3) / 4, 256, 0, stream>>>(esrc, ex, off, cw, a_src, a_dst,
                                            hbf, bias, out, n);
}

// Round 8
// 259.672 us; speedup vs baseline: 10.0578x; 1.1214x over previous
//
#include <hip/hip_runtime.h>
#include <math.h>

#define DIN 128
#define NH 4
#define HC 128
static constexpr float NEG_SLOPE = 0.2f;

typedef __attribute__((ext_vector_type(8))) short bf16x8;
typedef __attribute__((ext_vector_type(4))) float f32x4;

__device__ __forceinline__ float leaky(float x) { return x > 0.f ? x : NEG_SLOPE * x; }

// RNE float->bf16 (finite inputs)
__device__ __forceinline__ unsigned short f2bf(float f) {
  unsigned u = __float_as_uint(f);
  unsigned r = (u + 0x7fffu + ((u >> 16) & 1u)) >> 16;
  return (unsigned short)r;
}
__device__ __forceinline__ float bf_lo(unsigned u) { return __uint_as_float(u << 16); }
__device__ __forceinline__ float bf_hi(unsigned u) { return __uint_as_float(u & 0xffff0000u); }

static constexpr unsigned long long MASK40 = (1ull << 40) - 1;

// ---------------------------------------------------------------------------
// K0: zero cw + pre-swizzle W into the mfma B-fragment layout (one kernel).
__global__ void k_init(const float* __restrict__ W, short* __restrict__ bswz,
                       unsigned long long* __restrict__ cw, int n) {
  int g = blockIdx.x * blockDim.x + threadIdx.x;
  if (g < n) cw[g] = 0ull;
  if (g < 2048) {
    int ntile = g >> 8;
    int ks = (g >> 6) & 3;
    int lane = g & 63;
    int col = (ntile << 4) + (lane & 15);
    int kb = ks * 32 + ((lane >> 4) << 3);
    bf16x8 v;
#pragma unroll
    for (int j = 0; j < 8; ++j) v[j] = (short)f2bf(W[(kb + j) * HC + col]);
    ((bf16x8*)bswz)[g] = v;
  }
}

// ---------------------------------------------------------------------------
// K1 (fused): proj blocks + count blocks interleaved 3:2 so the MFMA-bound
// projection and the atomic-bound degree/weight count run CONCURRENTLY.
//   group = blockIdx.x/5 ; r = blockIdx.x%5
//   r<3  -> proj block pid = group*3+r   (4 waves, one 16-row tile each)
//   r>=3 -> count block cid = group*2+(r-3), grid-stride over edges
__global__ __launch_bounds__(256) void k_fused(
    const float* __restrict__ x, const short* __restrict__ bswz,
    const float* __restrict__ att_s, const float* __restrict__ att_d,
    unsigned short* __restrict__ hbf,
    float* __restrict__ a_src, float* __restrict__ a_dst, int n,
    const int* __restrict__ dst, const float* __restrict__ w,
    unsigned long long* __restrict__ cw, unsigned short* __restrict__ rank,
    int E, int CB) {
  int grp = blockIdx.x / 5;
  int r = blockIdx.x % 5;
  if (r >= 3) {
    // ---- count path ----
    int cid = grp * 2 + (r - 3);
    int stride = CB * 256;
    for (int e = cid * 256 + (int)threadIdx.x; e < E; e += stride) {
      int d = dst[e];
      unsigned long long fx = (unsigned long long)((double)w[e] * 4294967296.0);
      unsigned long long old = atomicAdd(&cw[d], (1ull << 40) | fx);
      rank[e] = (unsigned short)(old >> 40);
    }
    return;
  }
  // ---- proj path ----
  int pid = grp * 3 + r;
  int wtile = pid * 4 + (threadIdx.x >> 6);
  int ntiles = n >> 4;
  if (wtile >= ntiles) return;
  int lane = threadIdx.x & 63;
  int row0 = wtile << 4;

  int arow = row0 + (lane & 15);
  int kbase = (lane >> 4) << 3;
  const float* xr = x + (size_t)arow * DIN;
  bf16x8 a[4];
#pragma unroll
  for (int ks = 0; ks < 4; ++ks) {
    float4 lo = *(const float4*)(xr + ks * 32 + kbase);
    float4 hi = *(const float4*)(xr + ks * 32 + kbase + 4);
    bf16x8 v;
    v[0] = (short)f2bf(lo.x); v[1] = (short)f2bf(lo.y);
    v[2] = (short)f2bf(lo.z); v[3] = (short)f2bf(lo.w);
    v[4] = (short)f2bf(hi.x); v[5] = (short)f2bf(hi.y);
    v[6] = (short)f2bf(hi.z); v[7] = (short)f2bf(hi.w);
    a[ks] = v;
  }

  const bf16x8* B = (const bf16x8*)bswz;
  int crow_base = row0 + ((lane >> 4) << 2);
  int ccol_off = lane & 15;

  float ra[4] = {0.f, 0.f, 0.f, 0.f};
  float rd[4] = {0.f, 0.f, 0.f, 0.f};

#pragma unroll
  for (int ntile = 0; ntile < 8; ++ntile) {
    f32x4 acc = {0.f, 0.f, 0.f, 0.f};
#pragma unroll
    for (int ks = 0; ks < 4; ++ks)
      acc = __builtin_amdgcn_mfma_f32_16x16x32_bf16(a[ks], B[(ntile * 4 + ks) * 64 + lane], acc, 0, 0, 0);
    int col = (ntile << 4) + ccol_off;
    float as = att_s[col], ad = att_d[col];
#pragma unroll
    for (int i = 0; i < 4; ++i) {
      hbf[(size_t)(crow_base + i) * HC + col] = f2bf(acc[i]);
      ra[i] = fmaf(acc[i], as, ra[i]);
      rd[i] = fmaf(acc[i], ad, rd[i]);
    }
    if (ntile & 1) {
      int hh = ntile >> 1;
#pragma unroll
      for (int i = 0; i < 4; ++i) {
#pragma unroll
        for (int m = 1; m <= 8; m <<= 1) {
          ra[i] += __shfl_xor(ra[i], m, 64);
          rd[i] += __shfl_xor(rd[i], m, 64);
        }
        if ((lane & 15) == 0) {
          a_src[(crow_base + i) * NH + hh] = ra[i];
          a_dst[(crow_base + i) * NH + hh] = rd[i];
        }
        ra[i] = 0.f; rd[i] = 0.f;
      }
    }
  }
}

// ---------------------------------------------------------------------------
__global__ __launch_bounds__(256) void k_scan1(const unsigned long long* __restrict__ cw,
                                               int* __restrict__ off,
                                               int* __restrict__ bsum, int n) {
  __shared__ int lds[256];
  int b = blockIdx.x, t = threadIdx.x;
  int base = b * 1024 + t * 4;
  int v0 = 0, v1 = 0, v2 = 0, v3 = 0;
  if (base + 0 < n) v0 = (int)(cw[base + 0] >> 40);
  if (base + 1 < n) v1 = (int)(cw[base + 1] >> 40);
  if (base + 2 < n) v2 = (int)(cw[base + 2] >> 40);
  if (base + 3 < n) v3 = (int)(cw[base + 3] >> 40);
  int s = v0 + v1 + v2 + v3;
  lds[t] = s;
  __syncthreads();
  for (int ofs = 1; ofs < 256; ofs <<= 1) {
    int x = (t >= ofs) ? lds[t - ofs] : 0;
    __syncthreads();
    lds[t] += x;
    __syncthreads();
  }
  int run = (t > 0) ? lds[t - 1] : 0;
  if (t == 255) bsum[b] = lds[255];
  if (base + 0 < n) { off[base + 0] = run; run += v0; }
  if (base + 1 < n) { off[base + 1] = run; run += v1; }
  if (base + 2 < n) { off[base + 2] = run; run += v2; }
  if (base + 3 < n) { off[base + 3] = run; run += v3; }
}

__global__ __launch_bounds__(256) void k_scan2(int* __restrict__ bsum, int nb) {
  __shared__ int lds[256];
  int t = threadIdx.x;
  lds[t] = (t < nb) ? bsum[t] : 0;
  __syncthreads();
  for (int ofs = 1; ofs < 256; ofs <<= 1) {
    int x = (t >= ofs) ? lds[t - ofs] : 0;
    __syncthreads();
    lds[t] += x;
    __syncthreads();
  }
  int excl = (t > 0) ? lds[t - 1] : 0;
  if (t < nb) bsum[t] = excl;
}

__global__ void k_scan3(int* __restrict__ off, const int* __restrict__ bsum, int n, int E) {
  int i = blockIdx.x * blockDim.x + threadIdx.x;
  if (i < n) off[i] = off[i] + bsum[i >> 10];
  if (i == 0) off[n] = E;
}

// ---------------------------------------------------------------------------
// scatter edges into dst-sorted slots (off[d]+rank[e], NO atomics) and
// precompute per-(edge,head) exp.
__global__ void k_scatter(const int* __restrict__ ei, const float* __restrict__ w,
                          const int* __restrict__ off, const unsigned short* __restrict__ rank,
                          int* __restrict__ esrc, float4* __restrict__ ex4,
                          const float* __restrict__ a_src, const float* __restrict__ a_dst,
                          int E) {
  int e = blockIdx.x * blockDim.x + threadIdx.x;
  if (e >= E) return;
  int s = ei[e], d = ei[E + e];
  float wv = w[e];
  int p = off[d] + (int)rank[e];
  esrc[p] = s;
  float lw = log2f(wv);
  const float4 as = *reinterpret_cast<const float4*>(a_src + s * NH);
  const float4 ad = *reinterpret_cast<const float4*>(a_dst + d * NH);
  float4 ev;
  ev.x = expf(leaky(as.x + ad.x) + lw);
  ev.y = expf(leaky(as.y + ad.y) + lw);
  ev.z = expf(leaky(as.z + ad.z) + lw);
  ev.w = expf(leaky(as.w + ad.w) + lw);
  ex4[p] = ev;
}

// ---------------------------------------------------------------------------
// gather-aggregate: ONE wave per node; lane owns channels (2t,2t+1).
// Edge metadata (esrc, ex) staged 16 edges at a time with 2 coalesced loads,
// broadcast via shfl; inner loop is 1 gather-load + 2 FMA per edge.
__global__ __launch_bounds__(256) void k_gather(
    const int* __restrict__ esrc, const float* __restrict__ ex,
    const int* __restrict__ off, const unsigned long long* __restrict__ cw,
    const float* __restrict__ a_src, const float* __restrict__ a_dst,
    const unsigned short* __restrict__ hbf, const float* __restrict__ bias,
    float* __restrict__ out, int n) {
  int node = blockIdx.x * 4 + (threadIdx.x >> 6);
  if (node >= n) return;
  int t = threadIdx.x & 63;
  int j2 = t * 2;          // channels j2, j2+1 (same head)
  int hh = t >> 4;
  int beg = off[node], end = off[node + 1];
  float acc0 = 0.f, acc1 = 0.f, den = 0.f;

  int c0 = beg;
  // full 16-edge chunks, unrolled
  for (; c0 + 16 <= end; c0 += 16) {
    int sv = esrc[c0 + (t & 15)];        // lanes 16.. duplicate lanes 0..15
    float exv = ex[c0 * 4 + t];          // edge c0+(t>>2), head t&3
#pragma unroll
    for (int j = 0; j < 16; ++j) {
      int s = __shfl(sv, j, 64);
      float e = __shfl(exv, j * 4 + hh, 64);
      unsigned u = *(const unsigned*)(hbf + (size_t)s * HC + j2);
      den += e;
      acc0 = fmaf(e, bf_lo(u), acc0);
      acc1 = fmaf(e, bf_hi(u), acc1);
    }
  }
  // tail chunk
  int rem = end - c0;
  if (rem > 0) {
    int sv = ((t & 15) < rem) ? esrc[c0 + (t & 15)] : 0;
    float exv = (t < rem * 4) ? ex[c0 * 4 + t] : 0.f;
    for (int j = 0; j < rem; ++j) {
      int s = __shfl(sv, j, 64);
      float e = __shfl(exv, j * 4 + hh, 64);
      unsigned u = *(const unsigned*)(hbf + (size_t)s * HC + j2);
      den += e;
      acc0 = fmaf(e, bf_lo(u), acc0);
      acc1 = fmaf(e, bf_hi(u), acc1);
    }
  }

  // self-loop
  int deg = end - beg;
  float lw = 1.f;
  if (deg > 0) {
    double ws = (double)(cw[node] & MASK40) * (1.0 / 4294967296.0);
    lw = (float)(ws / (double)deg);
  }
  float exs = expf(leaky(a_src[node * NH + hh] + a_dst[node * NH + hh]) + log2f(lw));
  den += exs;
  unsigned us = *(const unsigned*)(hbf + (size_t)node * HC + j2);
  acc0 = fmaf(exs, bf_lo(us), acc0);
  acc1 = fmaf(exs, bf_hi(us), acc1);
  float rden = 1.f / den;
  float2 o;
  o.x = acc0 * rden + bias[j2];
  o.y = acc1 * rden + bias[j2 + 1];
  *(float2*)(out + (size_t)node * HC + j2) = o;
}

// ---------------------------------------------------------------------------
extern "C" void kernel_launch(void* const* d_in, const int* in_sizes, int n_in,
                              void* d_out, int out_size, void* d_ws, size_t ws_size,
                              hipStream_t stream) {
  const float* x       = (const float*)d_in[0];
  const int*   ei      = (const int*)d_in[1];   // [2][E]
  const float* eattr   = (const float*)d_in[2];
  const float* W       = (const float*)d_in[3];
  const float* att_src = (const float*)d_in[4];
  const float* att_dst = (const float*)d_in[5];
  const float* bias    = (const float*)d_in[6];
  float* out = (float*)d_out;

  const int n = in_sizes[0] / DIN;
  const int E = in_sizes[2];

  // workspace layout (n even, E even -> all boundaries stay 8/16B aligned)
  unsigned short* hbf = (unsigned short*)d_ws;            // n*HC bf16 (25.6 MB)
  float*  ex    = (float*)(hbf + (size_t)n * HC);         // E*4 f32
  int*    esrc  = (int*)(ex + (size_t)E * 4);             // E
  float*  a_src = (float*)(esrc + E);                     // n*4
  float*  a_dst = a_src + (size_t)n * NH;                 // n*4
  short*  bswz  = (short*)(a_dst + (size_t)n * NH);       // 16384 bf16 (32 KB)
  unsigned long long* cw = (unsigned long long*)(bswz + 16384);  // n u64
  int*    off   = (int*)(cw + n);                         // n+1
  unsigned short* rank = (unsigned short*)(off + n + 1);  // E u16
  int*    bsum  = (int*)(rank + E);                       // <=256

  const int* dst_idx = ei + E;
  int nb = (n + 1023) / 1024;
  int wavetiles = n >> 4;                 // n % 16 == 0
  int PB = (wavetiles + 3) / 4;           // proj blocks (4 waves each)
  int PB3 = ((PB + 2) / 3) * 3;           // round up to multiple of 3
  int CB = 2 * (PB3 / 3);                 // count blocks (3:2 interleave)
  int grid = PB3 + CB;                    // = 5 * (PB3/3)

  k_init<<<(n + 255) / 256, 256, 0, stream>>>(W, bswz, cw, n);
  k_fused<<<grid, 256, 0, stream>>>(x, bswz, att_src, att_dst, hbf, a_src, a_dst, n,
                                    dst_idx, eattr, cw, rank, E, CB);
  k_scan1<<<nb, 256, 0, stream>>>(cw, off, bsum, n);
  k_scan2<<<1, 256, 0, stream>>>(bsum, nb);
  k_scan3<<<(n + 255) / 256, 256, 0, stream>>>(off, bsum, n, E);
  k_scatter<<<(E + 255) / 256, 256, 0, stream>>>(ei, eattr, off, rank, esrc, (float4*)ex,
                                                 a_src, a_dst, E);
  k_gather<<<(n + 3) / 4, 256, 0, stream>>>(esrc, ex, off, cw, a_src, a_dst,
                                            hbf, bias, out, n);
}

// Round 9
// 213.143 us; speedup vs baseline: 12.2534x; 1.2183x over previous
//
#include <hip/hip_runtime.h>
#include <math.h>

#define DIN 128
#define NH 4
#define HC 128
static constexpr float NEG_SLOPE = 0.2f;

typedef __attribute__((ext_vector_type(8))) short bf16x8;
typedef __attribute__((ext_vector_type(4))) float f32x4;

__device__ __forceinline__ float leaky(float x) { return x > 0.f ? x : NEG_SLOPE * x; }

// RNE float->bf16 (finite inputs)
__device__ __forceinline__ unsigned short f2bf(float f) {
  unsigned u = __float_as_uint(f);
  unsigned r = (u + 0x7fffu + ((u >> 16) & 1u)) >> 16;
  return (unsigned short)r;
}
__device__ __forceinline__ float bf_lo(unsigned u) { return __uint_as_float(u << 16); }
__device__ __forceinline__ float bf_hi(unsigned u) { return __uint_as_float(u & 0xffff0000u); }

// ---------------------------------------------------------------------------
// K0: zero cnt + pre-swizzle W into the mfma B-fragment layout.
__global__ void k_init(const float* __restrict__ W, short* __restrict__ bswz,
                       unsigned* __restrict__ cnt, int n) {
  int g = blockIdx.x * blockDim.x + threadIdx.x;
  if (g < n) cnt[g] = 0u;
  if (g < 2048) {
    int ntile = g >> 8;
    int ks = (g >> 6) & 3;
    int lane = g & 63;
    int col = (ntile << 4) + (lane & 15);
    int kb = ks * 32 + ((lane >> 4) << 3);
    bf16x8 v;
#pragma unroll
    for (int j = 0; j < 8; ++j) v[j] = (short)f2bf(W[(kb + j) * HC + col]);
    ((bf16x8*)bswz)[g] = v;
  }
}

// ---------------------------------------------------------------------------
// K1 (fused): proj blocks + count blocks interleaved 3:2 (concurrent).
__global__ __launch_bounds__(256) void k_fused(
    const float* __restrict__ x, const short* __restrict__ bswz,
    const float* __restrict__ att_s, const float* __restrict__ att_d,
    unsigned short* __restrict__ hbf,
    float* __restrict__ a_src, float* __restrict__ a_dst, int n,
    const int* __restrict__ dst,
    unsigned* __restrict__ cnt, unsigned short* __restrict__ rank,
    int E, int CB) {
  int grp = blockIdx.x / 5;
  int r = blockIdx.x % 5;
  if (r >= 3) {
    // ---- count path: one 32-bit atomic per edge, old value = rank ----
    int cid = grp * 2 + (r - 3);
    int stride = CB * 256;
    for (int e = cid * 256 + (int)threadIdx.x; e < E; e += stride) {
      unsigned old = atomicAdd(&cnt[dst[e]], 1u);
      rank[e] = (unsigned short)old;
    }
    return;
  }
  // ---- proj path ----
  int pid = grp * 3 + r;
  int wtile = pid * 4 + (threadIdx.x >> 6);
  int ntiles = n >> 4;
  if (wtile >= ntiles) return;
  int lane = threadIdx.x & 63;
  int row0 = wtile << 4;

  int arow = row0 + (lane & 15);
  int kbase = (lane >> 4) << 3;
  const float* xr = x + (size_t)arow * DIN;
  bf16x8 a[4];
#pragma unroll
  for (int ks = 0; ks < 4; ++ks) {
    float4 lo = *(const float4*)(xr + ks * 32 + kbase);
    float4 hi = *(const float4*)(xr + ks * 32 + kbase + 4);
    bf16x8 v;
    v[0] = (short)f2bf(lo.x); v[1] = (short)f2bf(lo.y);
    v[2] = (short)f2bf(lo.z); v[3] = (short)f2bf(lo.w);
    v[4] = (short)f2bf(hi.x); v[5] = (short)f2bf(hi.y);
    v[6] = (short)f2bf(hi.z); v[7] = (short)f2bf(hi.w);
    a[ks] = v;
  }

  const bf16x8* B = (const bf16x8*)bswz;
  int crow_base = row0 + ((lane >> 4) << 2);
  int ccol_off = lane & 15;

  float ra[4] = {0.f, 0.f, 0.f, 0.f};
  float rd[4] = {0.f, 0.f, 0.f, 0.f};

#pragma unroll
  for (int ntile = 0; ntile < 8; ++ntile) {
    f32x4 acc = {0.f, 0.f, 0.f, 0.f};
#pragma unroll
    for (int ks = 0; ks < 4; ++ks)
      acc = __builtin_amdgcn_mfma_f32_16x16x32_bf16(a[ks], B[(ntile * 4 + ks) * 64 + lane], acc, 0, 0, 0);
    int col = (ntile << 4) + ccol_off;
    float as = att_s[col], ad = att_d[col];
#pragma unroll
    for (int i = 0; i < 4; ++i) {
      hbf[(size_t)(crow_base + i) * HC + col] = f2bf(acc[i]);
      ra[i] = fmaf(acc[i], as, ra[i]);
      rd[i] = fmaf(acc[i], ad, rd[i]);
    }
    if (ntile & 1) {
      int hh = ntile >> 1;
#pragma unroll
      for (int i = 0; i < 4; ++i) {
#pragma unroll
        for (int m = 1; m <= 8; m <<= 1) {
          ra[i] += __shfl_xor(ra[i], m, 64);
          rd[i] += __shfl_xor(rd[i], m, 64);
        }
        if ((lane & 15) == 0) {
          a_src[(crow_base + i) * NH + hh] = ra[i];
          a_dst[(crow_base + i) * NH + hh] = rd[i];
        }
        ra[i] = 0.f; rd[i] = 0.f;
      }
    }
  }
}

// ---------------------------------------------------------------------------
// scan1: block scans a 1024-chunk of cnt into off (exclusive), chunk total -> bsum
__global__ __launch_bounds__(256) void k_scan1(const unsigned* __restrict__ cnt,
                                               int* __restrict__ off,
                                               int* __restrict__ bsum, int n) {
  __shared__ int lds[256];
  int b = blockIdx.x, t = threadIdx.x;
  int base = b * 1024 + t * 4;
  int v0 = 0, v1 = 0, v2 = 0, v3 = 0;
  if (base + 0 < n) v0 = (int)cnt[base + 0];
  if (base + 1 < n) v1 = (int)cnt[base + 1];
  if (base + 2 < n) v2 = (int)cnt[base + 2];
  if (base + 3 < n) v3 = (int)cnt[base + 3];
  int s = v0 + v1 + v2 + v3;
  lds[t] = s;
  __syncthreads();
  for (int ofs = 1; ofs < 256; ofs <<= 1) {
    int x = (t >= ofs) ? lds[t - ofs] : 0;
    __syncthreads();
    lds[t] += x;
    __syncthreads();
  }
  int run = (t > 0) ? lds[t - 1] : 0;
  if (t == 255) bsum[b] = lds[255];
  if (base + 0 < n) { off[base + 0] = run; run += v0; }
  if (base + 1 < n) { off[base + 1] = run; run += v1; }
  if (base + 2 < n) { off[base + 2] = run; run += v2; }
  if (base + 3 < n) { off[base + 3] = run; run += v3; }
}

__global__ __launch_bounds__(256) void k_scan2(int* __restrict__ bsum, int nb) {
  __shared__ int lds[256];
  int t = threadIdx.x;
  lds[t] = (t < nb) ? bsum[t] : 0;
  __syncthreads();
  for (int ofs = 1; ofs < 256; ofs <<= 1) {
    int x = (t >= ofs) ? lds[t - ofs] : 0;
    __syncthreads();
    lds[t] += x;
    __syncthreads();
  }
  int excl = (t > 0) ? lds[t - 1] : 0;
  if (t < nb) bsum[t] = excl;
}

// ---------------------------------------------------------------------------
// scatter: pure permute, NO atomics, NO exp. edges2[p] = {src, bits(w)}.
// Final offset = off[d] + bsum[d>>10] + rank[e].
__global__ void k_scatter(const int* __restrict__ ei, const float* __restrict__ w,
                          const int* __restrict__ off, const int* __restrict__ bsum,
                          const unsigned short* __restrict__ rank,
                          int2* __restrict__ edges2, int E) {
  int e = blockIdx.x * blockDim.x + threadIdx.x;
  if (e >= E) return;
  int s = ei[e], d = ei[E + e];
  int p = off[d] + bsum[d >> 10] + (int)rank[e];
  edges2[p] = make_int2(s, __float_as_int(w[e]));
}

// ---------------------------------------------------------------------------
// gather-aggregate: ONE wave per node; lane owns channels (2t,2t+1).
// Per 16-edge chunk: 1 coalesced int2 stage, exp computed inline
// (lane t -> edge t>>2, head t&3: exactly 64 exps per chunk), wsum free.
__global__ __launch_bounds__(256) void k_gather(
    const int2* __restrict__ edges2,
    const int* __restrict__ off, const int* __restrict__ bsum,
    const float* __restrict__ a_src, const float* __restrict__ a_dst,
    const unsigned short* __restrict__ hbf, const float* __restrict__ bias,
    float* __restrict__ out, int n, int E) {
  int node = blockIdx.x * 4 + (threadIdx.x >> 6);
  if (node >= n) return;
  int t = threadIdx.x & 63;
  int j2 = t * 2;          // output channels j2, j2+1 (head hh = t>>4)
  int hh = t >> 4;
  int beg = off[node] + bsum[node >> 10];
  int end = (node == n - 1) ? E : off[node + 1] + bsum[(node + 1) >> 10];

  float adq = a_dst[node * NH + (t & 3)];  // a_dst for head (t&3) (exp path)
  float acc0 = 0.f, acc1 = 0.f, den = 0.f, wacc = 0.f;

  int c0 = beg;
  for (; c0 + 16 <= end; c0 += 16) {
    int2 ev = edges2[c0 + (t & 15)];
    int sq = __shfl(ev.x, t >> 2, 64);                 // src of edge t>>2
    float wq = __int_as_float(__shfl(ev.y, t >> 2, 64));
    float asq = a_src[sq * NH + (t & 3)];
    float et = expf(leaky(asq + adq) + log2f(wq));     // e for (edge t>>2, head t&3)
    wacc += ((t & 3) == 0) ? wq : 0.f;
#pragma unroll
    for (int j = 0; j < 16; ++j) {
      int s = __shfl(ev.x, j, 64);
      float e = __shfl(et, j * 4 + hh, 64);
      unsigned u = *(const unsigned*)(hbf + (size_t)s * HC + j2);
      den += e;
      acc0 = fmaf(e, bf_lo(u), acc0);
      acc1 = fmaf(e, bf_hi(u), acc1);
    }
  }
  // tail
  int rem = end - c0;
  if (rem > 0) {
    int2 ev = make_int2(0, __float_as_int(1.0f));
    if ((t & 15) < rem) ev = edges2[c0 + (t & 15)];
    int q = t >> 2;
    int sq = __shfl(ev.x, q, 64);
    float wq = __int_as_float(__shfl(ev.y, q, 64));
    float asq = a_src[sq * NH + (t & 3)];
    float et = expf(leaky(asq + adq) + log2f(wq));
    wacc += ((t & 3) == 0 && q < rem) ? wq : 0.f;
    for (int j = 0; j < rem; ++j) {
      int s = __shfl(ev.x, j, 64);
      float e = __shfl(et, j * 4 + hh, 64);
      unsigned u = *(const unsigned*)(hbf + (size_t)s * HC + j2);
      den += e;
      acc0 = fmaf(e, bf_lo(u), acc0);
      acc1 = fmaf(e, bf_hi(u), acc1);
    }
  }

  // wsum across wave (each edge counted once by its (t&3)==0 lane)
#pragma unroll
  for (int m = 1; m <= 32; m <<= 1) wacc += __shfl_xor(wacc, m, 64);

  int deg = end - beg;
  float lw = deg > 0 ? wacc / (float)deg : 1.f;
  float exs = expf(leaky(a_src[node * NH + hh] + a_dst[node * NH + hh]) + log2f(lw));
  den += exs;
  unsigned us = *(const unsigned*)(hbf + (size_t)node * HC + j2);
  acc0 = fmaf(exs, bf_lo(us), acc0);
  acc1 = fmaf(exs, bf_hi(us), acc1);
  float rden = 1.f / den;
  float2 o;
  o.x = acc0 * rden + bias[j2];
  o.y = acc1 * rden + bias[j2 + 1];
  *(float2*)(out + (size_t)node * HC + j2) = o;
}

// ---------------------------------------------------------------------------
extern "C" void kernel_launch(void* const* d_in, const int* in_sizes, int n_in,
                              void* d_out, int out_size, void* d_ws, size_t ws_size,
                              hipStream_t stream) {
  const float* x       = (const float*)d_in[0];
  const int*   ei      = (const int*)d_in[1];   // [2][E]
  const float* eattr   = (const float*)d_in[2];
  const float* W       = (const float*)d_in[3];
  const float* att_src = (const float*)d_in[4];
  const float* att_dst = (const float*)d_in[5];
  const float* bias    = (const float*)d_in[6];
  float* out = (float*)d_out;

  const int n = in_sizes[0] / DIN;
  const int E = in_sizes[2];

  // workspace layout (all boundaries 8/16B aligned: n, E even)
  unsigned short* hbf = (unsigned short*)d_ws;            // n*HC bf16 (25.6 MB)
  int2*   edges2 = (int2*)(hbf + (size_t)n * HC);         // E int2 (12.8 MB)
  float*  a_src  = (float*)(edges2 + E);                  // n*4
  float*  a_dst  = a_src + (size_t)n * NH;                // n*4
  short*  bswz   = (short*)(a_dst + (size_t)n * NH);      // 16384 bf16 (32 KB)
  unsigned* cnt  = (unsigned*)(bswz + 16384);             // n u32
  int*    off    = (int*)(cnt + n);                       // n+1
  unsigned short* rank = (unsigned short*)(off + n + 1);  // E u16
  int*    bsum   = (int*)(rank + E);                      // <=256

  const int* dst_idx = ei + E;
  int nb = (n + 1023) / 1024;
  int wavetiles = n >> 4;                 // n % 16 == 0
  int PB = (wavetiles + 3) / 4;           // proj blocks (4 waves each)
  int PB3 = ((PB + 2) / 3) * 3;
  int CB = 2 * (PB3 / 3);                 // count blocks (3:2 interleave)
  int grid = PB3 + CB;

  k_init<<<(n + 255) / 256, 256, 0, stream>>>(W, bswz, cnt, n);
  k_fused<<<grid, 256, 0, stream>>>(x, bswz, att_src, att_dst, hbf, a_src, a_dst, n,
                                    dst_idx, cnt, rank, E, CB);
  k_scan1<<<nb, 256, 0, stream>>>(cnt, off, bsum, n);
  k_scan2<<<1, 256, 0, stream>>>(bsum, nb);
  k_scatter<<<(E + 255) / 256, 256, 0, stream>>>(ei, eattr, off, bsum, rank, edges2, E);
  k_gather<<<(n + 3) / 4, 256, 0, stream>>>(edges2, off, bsum, a_src, a_dst,
                                            hbf, bias, out, n, E);
}